// Round 13
// baseline (498.468 us; speedup 1.0000x reference)
//
#include <hip/hip_runtime.h>
#include <hip/hip_bf16.h>

#define B_ 128
#define T_ 512
#define C_ 1024

typedef __attribute__((ext_vector_type(8))) short short8;
typedef __attribute__((ext_vector_type(4))) float f32x4;

__device__ __forceinline__ unsigned short f2bf(float f){
  unsigned u; __builtin_memcpy(&u, &f, 4);
  u += 0x7FFFu + ((u >> 16) & 1u);          // RNE
  return (unsigned short)(u >> 16);
}

// ---- async global->LDS 16B (LDS dest: wave-uniform base + lane*16)
typedef __attribute__((address_space(3))) unsigned lds_u32_t;
typedef __attribute__((address_space(1))) unsigned glb_u32_t;
typedef __attribute__((address_space(3))) char lds_char;
__device__ __forceinline__ void gload16(const void* g, void* l){
  __builtin_amdgcn_global_load_lds((const glb_u32_t*)g, (lds_u32_t*)l, 16, 0, 0);
}

// ---------------- cast f32 -> bf16 (vectorized; weights only now) ----------------
__global__ void cast_f32_bf16(const float* __restrict__ in, unsigned short* __restrict__ out, long n){
  long i = (long)blockIdx.x * blockDim.x + threadIdx.x;
  long stride = (long)gridDim.x * blockDim.x;
  for (long j = i * 4; j < n; j += stride * 4){
    float4 v = *(const float4*)(in + j);
    ushort4 o; o.x = f2bf(v.x); o.y = f2bf(v.y); o.z = f2bf(v.z); o.w = f2bf(v.w);
    *(ushort4*)(out + j) = o;
  }
}

// ---------------- transpose-cast W_proj (e,c) -> WpT (c,e) bf16 ----------------
__global__ void transpose_cast(const float* __restrict__ in, unsigned short* __restrict__ out){
  __shared__ float tile[32][33];
  int c0 = blockIdx.x * 32, e0 = blockIdx.y * 32;
  int tx = threadIdx.x, ty = threadIdx.y;     // (32,8)
  for (int r = 0; r < 32; r += 8)
    tile[ty + r][tx] = in[(size_t)(e0 + ty + r) * C_ + c0 + tx];
  __syncthreads();
  for (int r = 0; r < 32; r += 8)
    out[(size_t)(c0 + ty + r) * C_ + e0 + tx] = f2bf(tile[tx][ty + r]);
}

// ---------------- small bf16 GEMM (weight fuse), m97-style 128x128 ----------------
__global__ __launch_bounds__(256) void gemm_bt_bf16(
    const unsigned short* __restrict__ A,   // M x K
    const unsigned short* __restrict__ Bt,  // N x K
    unsigned short* __restrict__ Cc,        // M x N
    int M, int N, int K)
{
  __shared__ short As[128 * 32];
  __shared__ short Bs[128 * 32];
  const int tid  = threadIdx.x;
  const int lane = tid & 63;
  const int wave = tid >> 6;
  const int wr = wave >> 1, wc = wave & 1;
  const int lr = lane & 15, kg = lane >> 4;
  const int m0 = blockIdx.x * 128;
  const int n0 = blockIdx.y * 128;

  f32x4 acc[4][4];
  #pragma unroll
  for (int mi = 0; mi < 4; mi++)
    #pragma unroll
    for (int ni = 0; ni < 4; ni++)
      acc[mi][ni] = (f32x4){0.f, 0.f, 0.f, 0.f};

  const int r1 = tid >> 2, ch1 = tid & 3;
  char* abase = (char*)As + (tid & ~63) * 16;
  char* bbase = (char*)Bs + (tid & ~63) * 16;

  for (int k0 = 0; k0 < K; k0 += 32){
    __syncthreads();
    gload16(A  + (size_t)(m0 + r1)      * K + k0 + ch1 * 8, abase);
    gload16(A  + (size_t)(m0 + 64 + r1) * K + k0 + ch1 * 8, abase + 4096);
    gload16(Bt + (size_t)(n0 + r1)      * K + k0 + ch1 * 8, bbase);
    gload16(Bt + (size_t)(n0 + 64 + r1) * K + k0 + ch1 * 8, bbase + 4096);
    __syncthreads();

    short8 af[4], bfr[4];
    #pragma unroll
    for (int mi = 0; mi < 4; mi++)
      af[mi] = *(const short8*)&As[(wr * 64 + mi * 16 + lr) * 32 + kg * 8];
    #pragma unroll
    for (int ni = 0; ni < 4; ni++)
      bfr[ni] = *(const short8*)&Bs[(wc * 64 + ni * 16 + lr) * 32 + kg * 8];
    #pragma unroll
    for (int mi = 0; mi < 4; mi++)
      #pragma unroll
      for (int ni = 0; ni < 4; ni++)
        acc[mi][ni] = __builtin_amdgcn_mfma_f32_16x16x32_bf16(af[mi], bfr[ni], acc[mi][ni], 0, 0, 0);
  }

  #pragma unroll
  for (int mi = 0; mi < 4; mi++)
    #pragma unroll
    for (int ni = 0; ni < 4; ni++){
      int n = n0 + wc * 64 + ni * 16 + lr;
      int mb = m0 + wr * 64 + mi * 16 + kg * 4;
      #pragma unroll
      for (int j = 0; j < 4; j++)
        Cc[(size_t)(mb + j) * N + n] = f2bf(acc[mi][ni][j]);
    }
}

// ======= 256x256 GEMM, FUSED f32->bf16 A-staging, v3: BK=32, 64KB LDS, 2 blocks/CU =======
// LDS: A[slot][256][32]bf16 at slot*16384 (32KB), B[slot][256][32] at 32768+slot*16384.
// 64KB total -> TWO blocks/CU (r12 ran 128KB -> 1 block/CU, occupancy 22%, all stalls exposed).
// Per iter: 12 asm ds_reads + 32 MFMA keeps the m97-regime MFMA:read ratio; cross-block
// overlap hides read->MFMA serialization. Same SWZ involution + r12-verified addressing.
#define SWZ(x) ((x) ^ ((((x) >> 7) & 3) << 4))

#define STAGE_B32(kt) { \
  int d_ = wv * 1024 + ln * 16; int o_ = SWZ(d_); \
  gload16(Bg + (size_t)(n0 + (o_ >> 6)) * 1024 + (kt) * 32 + ((o_ >> 4) & 3) * 8, \
          ldsc + 32768 + ((kt) & 1) * 16384 + wv * 1024); \
  d_ += 8192; o_ = SWZ(d_); \
  gload16(Bg + (size_t)(n0 + (o_ >> 6)) * 1024 + (kt) * 32 + ((o_ >> 4) & 3) * 8, \
          ldsc + 32768 + ((kt) & 1) * 16384 + 8192 + wv * 1024); }

// load A k-tile (kt) f32 into regs: 2 units x 2 float4 = 4 float4 (64B/thread)
#define LOADA32(kt) { \
  _Pragma("unroll") for (int u = 0; u < 2; u++){ \
    int d_ = wv * 1024 + ln * 16 + u * 8192; \
    const float* p_ = Ag32 + (size_t)(m0 + (d_ >> 6)) * 1024 + (kt) * 32 + ((d_ >> 4) & 3) * 8; \
    areg[u][0] = *(const float4*)p_; \
    areg[u][1] = *(const float4*)(p_ + 4); } }

// cvt areg -> bf16, write to slot's swizzled dest (asm): 2 ds_write_b128
#define CVTWRITE32(slot) { \
  _Pragma("unroll") for (int u = 0; u < 2; u++){ \
    short8 w_; \
    _Pragma("unroll") for (int q = 0; q < 4; q++){ \
      w_[q]     = (short)f2bf(areg[u][0][q]); \
      w_[q + 4] = (short)f2bf(areg[u][1][q]); } \
    int d_ = wv * 1024 + ln * 16 + u * 8192; \
    unsigned ad_ = (unsigned)(size_t)(lds3 + (slot) * 16384 + SWZ(d_)); \
    asm volatile("ds_write_b128 %0, %1" :: "v"(ad_), "v"(w_)); } }

__global__ __launch_bounds__(512, 2) void gemm256_fused(
    const float* __restrict__ Ag32,         // 65536 x 1024 f32 (x)
    const unsigned short* __restrict__ Bg,  // 1024 x 1024 bf16 (W_f)
    unsigned short* __restrict__ vt)        // (C, B, T)
{
  extern __shared__ char ldsc[];            // 65536 B
  lds_char* lds3 = (lds_char*)ldsc;
  const int tid = threadIdx.x;
  const int ln  = tid & 63;
  const int wv  = tid >> 6;                 // 8 waves
  const int wr  = wv >> 2;                  // 2 M-waves (128 rows each)
  const int wc  = wv & 3;                   // 4 N-waves (64 cols each)
  const int lr  = ln & 15, kg = ln >> 4;
  // bijective XCD chunk: 4 n-tiles of each A-panel consecutive per XCD (L2 reuse for f32 A).
  const int id  = blockIdx.x;
  const int jj  = (id & 7) * 128 + (id >> 3);
  const int n0  = (jj & 3) * 256;
  const int m0  = (jj >> 2) * 256;

  f32x4 acc[8][4];
  #pragma unroll
  for (int mi = 0; mi < 8; mi++)
    #pragma unroll
    for (int ni = 0; ni < 4; ni++)
      acc[mi][ni] = (f32x4){0.f, 0.f, 0.f, 0.f};

  float4 areg[2][2];

  // prologue: tile0 -> slot0 (A via load+cvt+write, B via gload16)
  LOADA32(0);
  asm volatile("s_waitcnt vmcnt(0)");
  __builtin_amdgcn_sched_barrier(0);
  CVTWRITE32(0);
  __builtin_amdgcn_sched_barrier(0);
  STAGE_B32(0);
  __builtin_amdgcn_sched_barrier(0);
  asm volatile("s_waitcnt lgkmcnt(0)");     // A writes retired
  __builtin_amdgcn_sched_barrier(0);
  asm volatile("s_waitcnt vmcnt(0)");       // B(0) landed
  __builtin_amdgcn_sched_barrier(0);
  __builtin_amdgcn_s_barrier();

  short8 af[8], bfr[4];

  #pragma unroll 1
  for (int t = 0; t < 32; ++t){
    const int S = t & 1;

    // issue next tile's A reg-loads + B DMAs early; consumed at iter bottom
    if (t < 31){
      LOADA32(t + 1);
      __builtin_amdgcn_sched_barrier(0);
      STAGE_B32(t + 1);
      __builtin_amdgcn_sched_barrier(0);
    }

    // ---- 12 asm ds_reads from slot S -> 32 MFMA
    #pragma unroll
    for (int mi = 0; mi < 8; mi++){
      int off = S * 16384 + (wr * 128 + mi * 16 + lr) * 64 + kg * 16;
      unsigned a_ = (unsigned)(size_t)(lds3 + SWZ(off));
      asm volatile("ds_read_b128 %0, %1" : "=v"(af[mi]) : "v"(a_));
    }
    #pragma unroll
    for (int ni = 0; ni < 4; ni++){
      int off = 32768 + S * 16384 + (wc * 64 + ni * 16 + lr) * 64 + kg * 16;
      unsigned a_ = (unsigned)(size_t)(lds3 + SWZ(off));
      asm volatile("ds_read_b128 %0, %1" : "=v"(bfr[ni]) : "v"(a_));
    }
    asm volatile("s_waitcnt lgkmcnt(0)");
    __builtin_amdgcn_sched_barrier(0);
    __builtin_amdgcn_s_setprio(1);
    #pragma unroll
    for (int mi = 0; mi < 8; mi++)
      #pragma unroll
      for (int ni = 0; ni < 4; ni++)
        acc[mi][ni] = __builtin_amdgcn_mfma_f32_16x16x32_bf16(af[mi], bfr[ni], acc[mi][ni], 0, 0, 0);
    __builtin_amdgcn_s_setprio(0);
    __builtin_amdgcn_sched_barrier(0);

    // ---- bottom: consume A(t+1) regs (~1 MFMA phase of latency), write slot S^1
    if (t < 31){
      asm volatile("s_waitcnt vmcnt(0)");   // areg + B(t+1) landed
      __builtin_amdgcn_sched_barrier(0);
      CVTWRITE32(S ^ 1);
      __builtin_amdgcn_sched_barrier(0);
      asm volatile("s_waitcnt lgkmcnt(0)"); // A writes retired before barrier
      __builtin_amdgcn_sched_barrier(0);
    }
    __builtin_amdgcn_s_barrier();           // S^1 consistent; S free next iter
  }

  // epilogue: vt[(n*B + b)*T + t], m = b*512 + t   (r2/r6/r12-verified mapping)
  #pragma unroll
  for (int mi = 0; mi < 8; mi++)
    #pragma unroll
    for (int ni = 0; ni < 4; ni++){
      int n  = n0 + wc * 64 + ni * 16 + lr;
      int mb = m0 + wr * 128 + mi * 16 + kg * 4;
      int bb = mb >> 9, t = mb & 511;
      ushort4 o;
      o.x = f2bf(acc[mi][ni][0]); o.y = f2bf(acc[mi][ni][1]);
      o.z = f2bf(acc[mi][ni][2]); o.w = f2bf(acc[mi][ni][3]);
      *(ushort4*)&vt[((size_t)n * B_ + bb) * T_ + t] = o;
    }
}

// ---------------- Toeplitz band table, cheap gather version (r9) ----------------
__global__ __launch_bounds__(256) void band_prep2(const float* __restrict__ pw,
                                                  const float* __restrict__ line,
                                                  unsigned short* __restrict__ band){
  __shared__ unsigned short zrow[64];
  const int c = blockIdx.x, d32 = blockIdx.y;
  const int tid = threadIdx.x;
  if (tid < 63){
    int k = d32 * 32 - 31 + tid;      // k in [32*d32-31, 32*d32+31]
    float z = 0.f;
    if (k >= 0 && k < T_){
      float p = pw[c];
      float e = 2.0f + 100.0f / (1.0f + expf(-p));
      float lv = line[k];
      z = (lv > 0.f) ? expf(e * logf(lv)) : 0.f;
    }
    zrow[tid] = f2bf(z);
  }
  __syncthreads();
  const size_t base = ((size_t)c * 16 + d32) * 1280;
  #pragma unroll
  for (int q = 0; q < 5; q++){
    int idx = tid + q * 256;
    int i = idx / 40, j = idx - i * 40;
    unsigned short v = 0;
    if (j < 32){
      int qq = i - j + 31;            // in [0,62]
      v = zrow[qq];
    }
    band[base + idx] = v;
  }
}

// ---------------- conv via MFMA (r6 core + XCD decode; r9/r12-verified) ----------------
__global__ __launch_bounds__(256) void conv_mfma(
    const unsigned short* __restrict__ vt,    // (C, B, T) bf16
    const unsigned short* __restrict__ band,  // (C, 16, 32, 40) bf16
    const float* __restrict__ gain,           // (1,1,C)
    unsigned short* __restrict__ Ybf)         // (C, B, T) bf16, gain+relu applied
{
  __shared__ short Bs[128 * 32];      // v tile: 128 b x 32 s
  __shared__ short Ab[16 * 1280];     // up to 16 Toeplitz bands (40KB)
  const int id  = blockIdx.x;              // 4096 blocks
  const int xcd = id & 7;
  const int jj  = id >> 3;                 // 0..511
  const int c   = xcd + ((jj >> 2) << 3);  // 1024 channels
  const int t0  = (jj & 3) << 7;           // 4 t-tiles
  const int tid = threadIdx.x, lane = tid & 63, wave = tid >> 6;
  const int wr = wave >> 1, wc = wave & 1, lr = lane & 15, kg = lane >> 4;
  const int K  = t0 + 128;            // causal: s < t0+128
  const int nb = (t0 >> 5) + 4;       // bands d32 = 0..nb-1

  // stage all needed bands once (linear gload16)
  {
    const unsigned short* src = band + (size_t)c * (16 * 1280);
    const int nch = nb * 160;                      // 16B chunks
    for (int q0 = 0; q0 < nch; q0 += 256){
      int q = q0 + tid;
      char* dst = (char*)Ab + q0 * 16 + wave * 1024;   // wave-uniform
      if (q < nch) gload16(src + (size_t)q * 8, dst);
    }
  }

  f32x4 acc[4][4];
  #pragma unroll
  for (int mi = 0; mi < 4; mi++)
    #pragma unroll
    for (int ni = 0; ni < 4; ni++)
      acc[mi][ni] = (f32x4){0.f, 0.f, 0.f, 0.f};

  const int r1 = tid >> 2, ch1 = tid & 3;
  char* bbase = (char*)Bs + (tid & ~63) * 16;
  const size_t vbase = (size_t)c * B_ * T_;

  for (int k0 = 0; k0 < K; k0 += 32){
    __syncthreads();
    gload16(vt + vbase + (size_t)r1 * T_        + k0 + ch1 * 8, bbase);
    gload16(vt + vbase + (size_t)(64 + r1) * T_ + k0 + ch1 * 8, bbase + 4096);
    __syncthreads();

    short8 bfr[4];
    #pragma unroll
    for (int ni = 0; ni < 4; ni++)
      bfr[ni] = *(const short8*)&Bs[(wc * 64 + ni * 16 + lr) * 32 + kg * 8];

    const int dbase = ((t0 - k0) >> 5) + wr * 2;
    #pragma unroll
    for (int mi = 0; mi < 4; mi++){
      const int d32 = dbase + (mi >> 1);         // wave-uniform per mi
      if (d32 >= 0){
        const int i = ((mi & 1) << 4) + lr;      // row within band
        short8 af = *(const short8*)&Ab[d32 * 1280 + i * 40 + kg * 8];
        #pragma unroll
        for (int ni = 0; ni < 4; ni++)
          acc[mi][ni] = __builtin_amdgcn_mfma_f32_16x16x32_bf16(af, bfr[ni], acc[mi][ni], 0, 0, 0);
      }
    }
  }

  const float g = gain[c];
  #pragma unroll
  for (int mi = 0; mi < 4; mi++)
    #pragma unroll
    for (int ni = 0; ni < 4; ni++){
      int t = t0 + wr * 64 + mi * 16 + kg * 4;   // 4 consecutive t (j)
      int b = wc * 64 + ni * 16 + lr;
      ushort4 o;
      o.x = f2bf(fmaxf(acc[mi][ni][0] * g, 0.f));
      o.y = f2bf(fmaxf(acc[mi][ni][1] * g, 0.f));
      o.z = f2bf(fmaxf(acc[mi][ni][2] * g, 0.f));
      o.w = f2bf(fmaxf(acc[mi][ni][3] * g, 0.f));
      *(ushort4*)&Ybf[((size_t)c * B_ + b) * T_ + t] = o;
    }
}

// ---------------- final: (C,B,T) bf16 -> (B,T,C) f32 ----------------
__global__ __launch_bounds__(256) void final_out(const unsigned short* __restrict__ Ybf,
                                                 float* __restrict__ out){
  __shared__ unsigned short tile[64][72];
  const int c0 = blockIdx.x * 64;
  const int t0 = blockIdx.y * 64;
  const int b  = blockIdx.z;
  const int tid = threadIdx.x;
  const int cr = tid >> 4;
  const int t4 = (tid & 15) * 4;
  for (int q = 0; q < 64; q += 16){
    ushort4 u = *(const ushort4*)&Ybf[((size_t)(c0 + cr + q) * B_ + b) * T_ + t0 + t4];
    *(ushort4*)&tile[cr + q][t4] = u;
  }
  __syncthreads();
  const int tr = tid >> 4;
  const int c4 = (tid & 15) * 4;
  for (int q = 0; q < 64; q += 16){
    int t = tr + q;
    float4 o;
    o.x = __uint_as_float((unsigned)tile[c4 + 0][t] << 16);
    o.y = __uint_as_float((unsigned)tile[c4 + 1][t] << 16);
    o.z = __uint_as_float((unsigned)tile[c4 + 2][t] << 16);
    o.w = __uint_as_float((unsigned)tile[c4 + 3][t] << 16);
    *(float4*)&out[((size_t)b * T_ + t0 + t) * C_ + c0 + c4] = o;
  }
}

extern "C" void kernel_launch(void* const* d_in, const int* in_sizes, int n_in,
                              void* d_out, int out_size, void* d_ws, size_t ws_size,
                              hipStream_t stream)
{
  (void)in_sizes; (void)n_in; (void)out_size; (void)ws_size;
  const float* x    = (const float*)d_in[0];
  const float* Wp   = (const float*)d_in[1];
  const float* Wv   = (const float*)d_in[2];
  const float* gain = (const float*)d_in[3];
  const float* pw   = (const float*)d_in[4];
  const float* line = (const float*)d_in[5];
  float* out = (float*)d_out;

  // ws: [Ybf 128MB][WpT 2MB][Wv_bf 2MB][W_f 2MB]
  char* ws = (char*)d_ws;
  unsigned short* Ybf   = (unsigned short*)ws;
  unsigned short* WpT   = (unsigned short*)(ws + 134217728);
  unsigned short* Wv_bf = (unsigned short*)(ws + 134217728 + 2097152);
  unsigned short* W_f   = (unsigned short*)(ws + 134217728 + 2 * 2097152);
  // d_out (256MB f32) reused as scratch:
  unsigned short* vt    = (unsigned short*)d_out + 67108864;         // upper 128MB (dead after conv)
  unsigned short* bandp = (unsigned short*)d_out;                    // lower 40MB, written AFTER GEMM

  // weights
  cast_f32_bf16<<<256, 256, 0, stream>>>(Wv, Wv_bf, (long)C_ * C_);
  transpose_cast<<<dim3(32, 32), dim3(32, 8), 0, stream>>>(Wp, WpT);
  gemm_bt_bf16<<<dim3(8, 8), 256, 0, stream>>>(Wv_bf, WpT, W_f, C_, C_, C_);
  // v = x @ W_f^T with fused f32->bf16 A-staging (v3: BK=32, 64KB LDS, 2 blocks/CU)
  gemm256_fused<<<1024, 512, 65536, stream>>>(x, W_f, vt);
  // Toeplitz bands (d_out lower region)
  band_prep2<<<dim3(1024, 16), 256, 0, stream>>>(pw, line, bandp);
  // conv + gain + relu -> Ybf (C,B,T)
  conv_mfma<<<4096, 256, 0, stream>>>(vt, bandp, gain, Ybf);
  // transpose to (B,T,C) f32
  final_out<<<dim3(16, 8, 128), 256, 0, stream>>>(Ybf, out);
}

// Round 14
// 447.133 us; speedup vs baseline: 1.1148x; 1.1148x over previous
//
#include <hip/hip_runtime.h>
#include <hip/hip_bf16.h>

#define B_ 128
#define T_ 512
#define C_ 1024

typedef __attribute__((ext_vector_type(8))) short short8;
typedef __attribute__((ext_vector_type(4))) float f32x4;

__device__ __forceinline__ unsigned short f2bf(float f){
  unsigned u; __builtin_memcpy(&u, &f, 4);
  u += 0x7FFFu + ((u >> 16) & 1u);          // RNE
  return (unsigned short)(u >> 16);
}

// ---- async global->LDS 16B (LDS dest: wave-uniform base + lane*16)
typedef __attribute__((address_space(3))) unsigned lds_u32_t;
typedef __attribute__((address_space(1))) unsigned glb_u32_t;
typedef __attribute__((address_space(3))) char lds_char;
__device__ __forceinline__ void gload16(const void* g, void* l){
  __builtin_amdgcn_global_load_lds((const glb_u32_t*)g, (lds_u32_t*)l, 16, 0, 0);
}

// ---------------- cast f32 -> bf16 (vectorized; weights only) ----------------
__global__ void cast_f32_bf16(const float* __restrict__ in, unsigned short* __restrict__ out, long n){
  long i = (long)blockIdx.x * blockDim.x + threadIdx.x;
  long stride = (long)gridDim.x * blockDim.x;
  for (long j = i * 4; j < n; j += stride * 4){
    float4 v = *(const float4*)(in + j);
    ushort4 o; o.x = f2bf(v.x); o.y = f2bf(v.y); o.z = f2bf(v.z); o.w = f2bf(v.w);
    *(ushort4*)(out + j) = o;
  }
}

// ---------------- transpose-cast W_proj (e,c) -> WpT (c,e) bf16 ----------------
__global__ void transpose_cast(const float* __restrict__ in, unsigned short* __restrict__ out){
  __shared__ float tile[32][33];
  int c0 = blockIdx.x * 32, e0 = blockIdx.y * 32;
  int tx = threadIdx.x, ty = threadIdx.y;     // (32,8)
  for (int r = 0; r < 32; r += 8)
    tile[ty + r][tx] = in[(size_t)(e0 + ty + r) * C_ + c0 + tx];
  __syncthreads();
  for (int r = 0; r < 32; r += 8)
    out[(size_t)(c0 + ty + r) * C_ + e0 + tx] = f2bf(tile[tx][ty + r]);
}

// ---------------- small bf16 GEMM (weight fuse), m97-style 128x128 ----------------
__global__ __launch_bounds__(256) void gemm_bt_bf16(
    const unsigned short* __restrict__ A,   // M x K
    const unsigned short* __restrict__ Bt,  // N x K
    unsigned short* __restrict__ Cc,        // M x N
    int M, int N, int K)
{
  __shared__ short As[128 * 32];
  __shared__ short Bs[128 * 32];
  const int tid  = threadIdx.x;
  const int lane = tid & 63;
  const int wave = tid >> 6;
  const int wr = wave >> 1, wc = wave & 1;
  const int lr = lane & 15, kg = lane >> 4;
  const int m0 = blockIdx.x * 128;
  const int n0 = blockIdx.y * 128;

  f32x4 acc[4][4];
  #pragma unroll
  for (int mi = 0; mi < 4; mi++)
    #pragma unroll
    for (int ni = 0; ni < 4; ni++)
      acc[mi][ni] = (f32x4){0.f, 0.f, 0.f, 0.f};

  const int r1 = tid >> 2, ch1 = tid & 3;
  char* abase = (char*)As + (tid & ~63) * 16;
  char* bbase = (char*)Bs + (tid & ~63) * 16;

  for (int k0 = 0; k0 < K; k0 += 32){
    __syncthreads();
    gload16(A  + (size_t)(m0 + r1)      * K + k0 + ch1 * 8, abase);
    gload16(A  + (size_t)(m0 + 64 + r1) * K + k0 + ch1 * 8, abase + 4096);
    gload16(Bt + (size_t)(n0 + r1)      * K + k0 + ch1 * 8, bbase);
    gload16(Bt + (size_t)(n0 + 64 + r1) * K + k0 + ch1 * 8, bbase + 4096);
    __syncthreads();

    short8 af[4], bfr[4];
    #pragma unroll
    for (int mi = 0; mi < 4; mi++)
      af[mi] = *(const short8*)&As[(wr * 64 + mi * 16 + lr) * 32 + kg * 8];
    #pragma unroll
    for (int ni = 0; ni < 4; ni++)
      bfr[ni] = *(const short8*)&Bs[(wc * 64 + ni * 16 + lr) * 32 + kg * 8];
    #pragma unroll
    for (int mi = 0; mi < 4; mi++)
      #pragma unroll
      for (int ni = 0; ni < 4; ni++)
        acc[mi][ni] = __builtin_amdgcn_mfma_f32_16x16x32_bf16(af[mi], bfr[ni], acc[mi][ni], 0, 0, 0);
  }

  #pragma unroll
  for (int mi = 0; mi < 4; mi++)
    #pragma unroll
    for (int ni = 0; ni < 4; ni++){
      int n = n0 + wc * 64 + ni * 16 + lr;
      int mb = m0 + wr * 64 + mi * 16 + kg * 4;
      #pragma unroll
      for (int j = 0; j < 4; j++)
        Cc[(size_t)(mb + j) * N + n] = f2bf(acc[mi][ni][j]);
    }
}

// ======= 256x256 GEMM, FUSED f32->bf16 A-staging (r12-exact, 247us verified) =======
// Single-buffered fragments, depth-1 A pipeline (issue loads at iter top, cvt+ds_write
// at iter bottom after both MFMA phases). BK=64, 128KB LDS. All LDS ops inline-asm.
#define SWZ(x) ((x) ^ ((((x) >> 7) & 3) << 4))

#define STAGE_B(kt, kh) { \
  int d_ = wv * 1024 + ln * 16; int o_ = SWZ(d_); \
  gload16(Bg + (size_t)(n0 + (o_ >> 6)) * 1024 + (kt) * 64 + (kh) * 32 + ((o_ >> 4) & 3) * 8, \
          ldsc + 65536 + ((kt) & 1) * 32768 + (kh) * 16384 + wv * 1024); \
  d_ += 8192; o_ = SWZ(d_); \
  gload16(Bg + (size_t)(n0 + (o_ >> 6)) * 1024 + (kt) * 64 + (kh) * 32 + ((o_ >> 4) & 3) * 8, \
          ldsc + 65536 + ((kt) & 1) * 32768 + (kh) * 16384 + 8192 + wv * 1024); }

#define LOADA(kt) { \
  _Pragma("unroll") for (int kh = 0; kh < 2; kh++) \
    _Pragma("unroll") for (int hf = 0; hf < 2; hf++){ \
      const float* p_ = Ag32 + (size_t)(m0 + rowA + hf * 128) * 1024 + (kt) * 64 + kh * 32 + c8 * 8; \
      areg[kh][hf][0] = *(const float4*)p_; \
      areg[kh][hf][1] = *(const float4*)(p_ + 4); } }

#define CVTWRITE(slot) { \
  _Pragma("unroll") for (int kh = 0; kh < 2; kh++) \
    _Pragma("unroll") for (int hf = 0; hf < 2; hf++){ \
      short8 w_; \
      _Pragma("unroll") for (int q = 0; q < 4; q++){ \
        w_[q]     = (short)f2bf(areg[kh][hf][0][q]); \
        w_[q + 4] = (short)f2bf(areg[kh][hf][1][q]); } \
      int d_ = wv * 1024 + ln * 16 + hf * 8192; \
      unsigned ad_ = (unsigned)(size_t)(lds3 + (slot) * 32768 + kh * 16384 + SWZ(d_)); \
      asm volatile("ds_write_b128 %0, %1" :: "v"(ad_), "v"(w_)); } }

__global__ __launch_bounds__(512, 2) void gemm256_fused(
    const float* __restrict__ Ag32,         // 65536 x 1024 f32 (x)
    const unsigned short* __restrict__ Bg,  // 1024 x 1024 bf16 (W_f)
    unsigned short* __restrict__ vt)        // (C, B, T)
{
  extern __shared__ char ldsc[];            // 131072 B
  lds_char* lds3 = (lds_char*)ldsc;
  const int tid = threadIdx.x;
  const int ln  = tid & 63;
  const int wv  = tid >> 6;                 // 8 waves
  const int wr  = wv >> 2;                  // 2 M-waves (128 rows each)
  const int wc  = wv & 3;                   // 4 N-waves (64 cols each)
  const int lr  = ln & 15, kg = ln >> 4;
  const int rowA = wv * 16 + (ln >> 2);     // A staging row (0..127), +128 for hf=1
  const int c8   = ln & 3;                  // A staging 8-f32 chunk within 32-col k-half
  // bijective XCD chunk: 4 n-tiles of each A-panel consecutive per XCD.
  const int id  = blockIdx.x;
  const int jj  = (id & 7) * 128 + (id >> 3);
  const int n0  = (jj & 3) * 256;
  const int m0  = (jj >> 2) * 256;

  f32x4 acc[8][4];
  #pragma unroll
  for (int mi = 0; mi < 8; mi++)
    #pragma unroll
    for (int ni = 0; ni < 4; ni++)
      acc[mi][ni] = (f32x4){0.f, 0.f, 0.f, 0.f};

  float4 areg[2][2][2];

  // prologue: tile0 -> slot0 (A via load+cvt+write, B via gload16)
  LOADA(0);
  asm volatile("s_waitcnt vmcnt(0)");
  __builtin_amdgcn_sched_barrier(0);
  CVTWRITE(0);
  __builtin_amdgcn_sched_barrier(0);
  STAGE_B(0, 0); STAGE_B(0, 1);
  __builtin_amdgcn_sched_barrier(0);
  asm volatile("s_waitcnt lgkmcnt(0)");     // A writes retired
  __builtin_amdgcn_sched_barrier(0);
  asm volatile("s_waitcnt vmcnt(0)");       // B(0) landed
  __builtin_amdgcn_sched_barrier(0);
  __builtin_amdgcn_s_barrier();

  short8 af[8], bfr[4];                     // single-buffered fragments

  #pragma unroll 1
  for (int t = 0; t < 16; ++t){
    const int S = t & 1;

    // issue next tile's A reg-loads + B DMAs early; consumed at iter bottom
    if (t < 15){
      LOADA(t + 1);
      __builtin_amdgcn_sched_barrier(0);
      STAGE_B(t + 1, 0); STAGE_B(t + 1, 1);
      __builtin_amdgcn_sched_barrier(0);
    }

    // ---- K-half 0: 12 reads -> wait -> 32 MFMA
    #pragma unroll
    for (int mi = 0; mi < 8; mi++){
      int off = S * 32768 + (wr * 128 + mi * 16 + lr) * 64 + kg * 16;
      unsigned a_ = (unsigned)(size_t)(lds3 + SWZ(off));
      asm volatile("ds_read_b128 %0, %1" : "=v"(af[mi]) : "v"(a_));
    }
    #pragma unroll
    for (int ni = 0; ni < 4; ni++){
      int off = 65536 + S * 32768 + (wc * 64 + ni * 16 + lr) * 64 + kg * 16;
      unsigned a_ = (unsigned)(size_t)(lds3 + SWZ(off));
      asm volatile("ds_read_b128 %0, %1" : "=v"(bfr[ni]) : "v"(a_));
    }
    asm volatile("s_waitcnt lgkmcnt(0)");
    __builtin_amdgcn_sched_barrier(0);
    __builtin_amdgcn_s_setprio(1);
    #pragma unroll
    for (int mi = 0; mi < 8; mi++)
      #pragma unroll
      for (int ni = 0; ni < 4; ni++)
        acc[mi][ni] = __builtin_amdgcn_mfma_f32_16x16x32_bf16(af[mi], bfr[ni], acc[mi][ni], 0, 0, 0);
    __builtin_amdgcn_s_setprio(0);
    __builtin_amdgcn_sched_barrier(0);

    // ---- K-half 1: 12 reads (reuse regs) -> wait -> 32 MFMA
    #pragma unroll
    for (int mi = 0; mi < 8; mi++){
      int off = S * 32768 + 16384 + (wr * 128 + mi * 16 + lr) * 64 + kg * 16;
      unsigned a_ = (unsigned)(size_t)(lds3 + SWZ(off));
      asm volatile("ds_read_b128 %0, %1" : "=v"(af[mi]) : "v"(a_));
    }
    #pragma unroll
    for (int ni = 0; ni < 4; ni++){
      int off = 65536 + S * 32768 + 16384 + (wc * 64 + ni * 16 + lr) * 64 + kg * 16;
      unsigned a_ = (unsigned)(size_t)(lds3 + SWZ(off));
      asm volatile("ds_read_b128 %0, %1" : "=v"(bfr[ni]) : "v"(a_));
    }
    asm volatile("s_waitcnt lgkmcnt(0)");
    __builtin_amdgcn_sched_barrier(0);
    __builtin_amdgcn_s_setprio(1);
    #pragma unroll
    for (int mi = 0; mi < 8; mi++)
      #pragma unroll
      for (int ni = 0; ni < 4; ni++)
        acc[mi][ni] = __builtin_amdgcn_mfma_f32_16x16x32_bf16(af[mi], bfr[ni], acc[mi][ni], 0, 0, 0);
    __builtin_amdgcn_s_setprio(0);
    __builtin_amdgcn_sched_barrier(0);

    // ---- bottom: consume A(t+1) regs, write slot S^1
    if (t < 15){
      asm volatile("s_waitcnt vmcnt(0)");   // areg + B(t+1) landed
      __builtin_amdgcn_sched_barrier(0);
      CVTWRITE(S ^ 1);
      __builtin_amdgcn_sched_barrier(0);
      asm volatile("s_waitcnt lgkmcnt(0)"); // A writes retired before barrier
      __builtin_amdgcn_sched_barrier(0);
    }
    __builtin_amdgcn_s_barrier();           // S^1 consistent; S free next iter
  }

  // epilogue: vt[(n*B + b)*T + t], m = b*512 + t
  #pragma unroll
  for (int mi = 0; mi < 8; mi++)
    #pragma unroll
    for (int ni = 0; ni < 4; ni++){
      int n  = n0 + wc * 64 + ni * 16 + lr;
      int mb = m0 + wr * 128 + mi * 16 + kg * 4;
      int bb = mb >> 9, t = mb & 511;
      ushort4 o;
      o.x = f2bf(acc[mi][ni][0]); o.y = f2bf(acc[mi][ni][1]);
      o.z = f2bf(acc[mi][ni][2]); o.w = f2bf(acc[mi][ni][3]);
      *(ushort4*)&vt[((size_t)n * B_ + bb) * T_ + t] = o;
    }
}

// ---------------- conv via MFMA, band table FUSED (computed in-LDS, no global table) ----
// zbuf[k] = line[k]^(2+100*sigmoid(pw_c)) computed per block (<=512 transcendental pairs),
// then Ab[d32][i][j] = zbuf[32*d32+i-j] filled in-LDS (same layout band_prep2 produced).
__global__ __launch_bounds__(256) void conv_mfma(
    const unsigned short* __restrict__ vt,    // (C, B, T) bf16
    const float* __restrict__ pw,             // (C)
    const float* __restrict__ line,           // (T)
    const float* __restrict__ gain,           // (1,1,C)
    unsigned short* __restrict__ Ybf)         // (C, B, T) bf16, gain+relu applied
{
  __shared__ short Bs[128 * 32];              // v tile: 128 b x 32 s (8KB)
  __shared__ short Ab[16 * 1280];             // up to 16 Toeplitz bands (40KB)
  __shared__ unsigned short zbuf[512];        // 1KB
  const int id  = blockIdx.x;                 // 4096 blocks
  const int xcd = id & 7;
  const int jj  = id >> 3;                    // 0..511
  const int c   = xcd + ((jj >> 2) << 3);     // 1024 channels
  const int t0  = (jj & 3) << 7;              // 4 t-tiles
  const int tid = threadIdx.x, lane = tid & 63, wave = tid >> 6;
  const int wr = wave >> 1, wc = wave & 1, lr = lane & 15, kg = lane >> 4;
  const int K  = t0 + 128;                    // causal: s < t0+128
  const int nb = (t0 >> 5) + 4;               // bands d32 = 0..nb-1

  // ---- fused band computation (replaces band_prep2 + gload16 staging)
  {
    float p = pw[c];
    float e = 2.0f + 100.0f / (1.0f + expf(-p));
    for (int k = tid; k < K; k += 256){       // K = 32*nb <= 512
      float lv = line[k];
      float z = (lv > 0.f) ? expf(e * logf(lv)) : 0.f;
      zbuf[k] = f2bf(z);
    }
  }
  __syncthreads();
  for (int idx = tid; idx < nb * 1280; idx += 256){
    int i = idx / 40, j = idx - i * 40;       // i = global band row
    int d32 = i >> 5, ii = i & 31;
    int k = d32 * 32 + ii - j;
    unsigned short v = 0;
    if (j < 32 && k >= 0) v = zbuf[k];        // k < 32*nb = K always
    Ab[idx] = v;
  }
  // visibility: covered by iteration-0's __syncthreads() below

  f32x4 acc[4][4];
  #pragma unroll
  for (int mi = 0; mi < 4; mi++)
    #pragma unroll
    for (int ni = 0; ni < 4; ni++)
      acc[mi][ni] = (f32x4){0.f, 0.f, 0.f, 0.f};

  const int r1 = tid >> 2, ch1 = tid & 3;
  char* bbase = (char*)Bs + (tid & ~63) * 16;
  const size_t vbase = (size_t)c * B_ * T_;

  for (int k0 = 0; k0 < K; k0 += 32){
    __syncthreads();
    gload16(vt + vbase + (size_t)r1 * T_        + k0 + ch1 * 8, bbase);
    gload16(vt + vbase + (size_t)(64 + r1) * T_ + k0 + ch1 * 8, bbase + 4096);
    __syncthreads();

    short8 bfr[4];
    #pragma unroll
    for (int ni = 0; ni < 4; ni++)
      bfr[ni] = *(const short8*)&Bs[(wc * 64 + ni * 16 + lr) * 32 + kg * 8];

    const int dbase = ((t0 - k0) >> 5) + wr * 2;
    #pragma unroll
    for (int mi = 0; mi < 4; mi++){
      const int d32 = dbase + (mi >> 1);         // wave-uniform per mi
      if (d32 >= 0){
        const int i = ((mi & 1) << 4) + lr;      // row within band
        short8 af = *(const short8*)&Ab[d32 * 1280 + i * 40 + kg * 8];
        #pragma unroll
        for (int ni = 0; ni < 4; ni++)
          acc[mi][ni] = __builtin_amdgcn_mfma_f32_16x16x32_bf16(af, bfr[ni], acc[mi][ni], 0, 0, 0);
      }
    }
  }

  const float g = gain[c];
  #pragma unroll
  for (int mi = 0; mi < 4; mi++)
    #pragma unroll
    for (int ni = 0; ni < 4; ni++){
      int t = t0 + wr * 64 + mi * 16 + kg * 4;   // 4 consecutive t (j)
      int b = wc * 64 + ni * 16 + lr;
      ushort4 o;
      o.x = f2bf(fmaxf(acc[mi][ni][0] * g, 0.f));
      o.y = f2bf(fmaxf(acc[mi][ni][1] * g, 0.f));
      o.z = f2bf(fmaxf(acc[mi][ni][2] * g, 0.f));
      o.w = f2bf(fmaxf(acc[mi][ni][3] * g, 0.f));
      *(ushort4*)&Ybf[((size_t)c * B_ + b) * T_ + t] = o;
    }
}

// ---------------- final: (C,B,T) bf16 -> (B,T,C) f32 ----------------
__global__ __launch_bounds__(256) void final_out(const unsigned short* __restrict__ Ybf,
                                                 float* __restrict__ out){
  __shared__ unsigned short tile[64][72];
  const int c0 = blockIdx.x * 64;
  const int t0 = blockIdx.y * 64;
  const int b  = blockIdx.z;
  const int tid = threadIdx.x;
  const int cr = tid >> 4;
  const int t4 = (tid & 15) * 4;
  for (int q = 0; q < 64; q += 16){
    ushort4 u = *(const ushort4*)&Ybf[((size_t)(c0 + cr + q) * B_ + b) * T_ + t0 + t4];
    *(ushort4*)&tile[cr + q][t4] = u;
  }
  __syncthreads();
  const int tr = tid >> 4;
  const int c4 = (tid & 15) * 4;
  for (int q = 0; q < 64; q += 16){
    int t = tr + q;
    float4 o;
    o.x = __uint_as_float((unsigned)tile[c4 + 0][t] << 16);
    o.y = __uint_as_float((unsigned)tile[c4 + 1][t] << 16);
    o.z = __uint_as_float((unsigned)tile[c4 + 2][t] << 16);
    o.w = __uint_as_float((unsigned)tile[c4 + 3][t] << 16);
    *(float4*)&out[((size_t)b * T_ + t0 + t) * C_ + c0 + c4] = o;
  }
}

extern "C" void kernel_launch(void* const* d_in, const int* in_sizes, int n_in,
                              void* d_out, int out_size, void* d_ws, size_t ws_size,
                              hipStream_t stream)
{
  (void)in_sizes; (void)n_in; (void)out_size; (void)ws_size;
  const float* x    = (const float*)d_in[0];
  const float* Wp   = (const float*)d_in[1];
  const float* Wv   = (const float*)d_in[2];
  const float* gain = (const float*)d_in[3];
  const float* pw   = (const float*)d_in[4];
  const float* line = (const float*)d_in[5];
  float* out = (float*)d_out;

  // ws: [Ybf 128MB][WpT 2MB][Wv_bf 2MB][W_f 2MB]
  char* ws = (char*)d_ws;
  unsigned short* Ybf   = (unsigned short*)ws;
  unsigned short* WpT   = (unsigned short*)(ws + 134217728);
  unsigned short* Wv_bf = (unsigned short*)(ws + 134217728 + 2097152);
  unsigned short* W_f   = (unsigned short*)(ws + 134217728 + 2 * 2097152);
  // d_out (256MB f32) reused as scratch:
  unsigned short* vt    = (unsigned short*)d_out + 67108864;         // upper 128MB (dead after conv)

  // weights
  cast_f32_bf16<<<256, 256, 0, stream>>>(Wv, Wv_bf, (long)C_ * C_);
  transpose_cast<<<dim3(32, 32), dim3(32, 8), 0, stream>>>(Wp, WpT);
  gemm_bt_bf16<<<dim3(8, 8), 256, 0, stream>>>(Wv_bf, WpT, W_f, C_, C_, C_);
  // v = x @ W_f^T with fused f32->bf16 A-staging (r12-exact); writes (C,B,T)
  gemm256_fused<<<1024, 512, 131072, stream>>>(x, W_f, vt);
  // conv + gain + relu -> Ybf (C,B,T); band table computed in-kernel (no global table)
  conv_mfma<<<4096, 256, 0, stream>>>(vt, pw, line, gain, Ybf);
  // transpose to (B,T,C) f32
  final_out<<<dim3(16, 8, 128), 256, 0, stream>>>(Ybf, out);
}